// Round 2
// baseline (313.215 us; speedup 1.0000x reference)
//
#include <hip/hip_runtime.h>
#include <hip/hip_cooperative_groups.h>

namespace cg = cooperative_groups;

// LogisticRegressionRBF: out[k] = sigmoid( sum_n w[n]*exp(-||x_k - c_n||^2) + b )
// K=65536, N=4096, M=64. fp32 in/out.
//
// R9: kill the 256 MiB d_ws poison-fill (~43 us, ~48% of measured dur -- top-5
// dispatches this round were all fillBufferAligned at 6.2 TB/s) by using NO
// workspace: stage fp8 B-fragments in the OUTPUT buffer (256 KB == exactly
// N*M fp8) and per-center meta in LDS, inside ONE cooperative kernel with
// grid syncs. Fallback to the proven R8 two-kernel ws path if cooperative
// launch is rejected under graph capture.
// Main-loop changes vs R8 (main ~38 us):
//   - 2-chunk-deep B prefetch, consume-then-reload order (R8 issued loads
//     BEFORE the consuming MFMAs -> vmcnt drain exposed L2 latency per iter)
//   - tile-staggered screen: screen tile i while tile i+1's MFMA is in
//     flight (32 live acc regs, not 64); no runtime-indexed reg arrays
//   - thresholds tq and w from LDS (ds_read, no vmcnt), bf16-packed
//     (threshold slack: TSKIP margin >> bf16 ulp ~0.25)

#define KOBS 65536
#define NCENT 4096
#define MFEAT 64
#define NCHUNK 32                    // 4096 / 128 centers per chunk

#define SCALE_A 2.8853900817779268f  // 2*log2(e)
#define QS      1.4426950408889634f  // log2(e)
#define TSKIP   -60.0f

typedef __attribute__((ext_vector_type(4)))  float float4v;
typedef __attribute__((ext_vector_type(2)))  float float2v;
typedef __attribute__((ext_vector_type(16))) float float16v;
typedef __attribute__((ext_vector_type(8)))  int   int8v;
typedef __attribute__((ext_vector_type(8)))  short short8;

#if __has_builtin(__builtin_amdgcn_exp2f)
#define EXP2F(x) __builtin_amdgcn_exp2f(x)
#else
#define EXP2F(x) exp2f(x)
#endif

static __device__ inline unsigned short f2bfu(float f) {
    unsigned int u = __float_as_uint(f);
    return (unsigned short)((u + 0x7fffu + ((u >> 16) & 1u)) >> 16);
}

#define MFMA(A, B, C) __builtin_amdgcn_mfma_scale_f32_32x32x64_f8f6f4( \
    (A), (B), (C), 0, 0, 0, 0x7f7f7f7f, 0, 0x7f7f7f7f)

// ============================ fused cooperative kernel =====================
// grid 512 x block 512. Each block: 128 output rows (2 row-tiles of 64).
// Wave wv: rt = wv>>2 selects row-tile, wq = wv&3 selects center quarter.
__global__ __launch_bounds__(512, 4) void rbf_fused(
    const float* __restrict__ x, const float* __restrict__ xb,
    const float* __restrict__ w, const float* __restrict__ bptr,
    float* __restrict__ out) {
    __shared__ unsigned int meta_s[NCENT];   // {bf16 tq, bf16 w} per center
    __shared__ float x2s[128];
    __shared__ float zl[128];

    const int tid  = threadIdx.x;
    const int wv   = tid >> 6;
    const int lane = tid & 63;
    const int ll   = lane & 31;
    const int lh   = lane >> 5;
    const int rt   = wv >> 2;        // row-tile within block
    const int wq   = wv & 3;         // center quarter
    const int bid  = (int)blockIdx.x;

    cg::grid_group grid = cg::this_grid();

    // ---- S0: per-center meta -> out[0:16K]; keep xb value for S2 ----
    const int n = bid * 8 + wv;                       // 512*8 = 4096 centers
    const float cv = xb[n * MFEAT + lane];
    {
        float s = cv * cv;
        #pragma unroll
        for (int off = 32; off > 0; off >>= 1) s += __shfl_xor(s, off, 64);
        if (lane == 0) {
            const float tq = TSKIP + QS * s;          // = TSKIP - q_n
            ((unsigned int*)out)[n] =
                ((unsigned int)f2bfu(tq) << 16) | f2bfu(w[n]);
        }
    }

    // ---- A fragments (fp8, pre-scaled by 2*log2e) + row norms (overlaps) --
    // A-frag layout for 32x32x64: lane l holds row l&31, k = (l>>5)*32 + byte.
    const int r0e = bid * 128 + rt * 64;
    int8v af0, af1;
    #pragma unroll
    for (int t = 0; t < 2; ++t) {
        const float* xr = x + (size_t)(r0e + t * 32 + ll) * MFEAT + lh * 32;
        int8v a;
        float ss = 0.0f;
        #pragma unroll
        for (int rg = 0; rg < 8; ++rg) {
            float4v v = *(const float4v*)(xr + rg * 4);
            ss = fmaf(v[0], v[0], ss); ss = fmaf(v[1], v[1], ss);
            ss = fmaf(v[2], v[2], ss); ss = fmaf(v[3], v[3], ss);
            int pk = __builtin_amdgcn_cvt_pk_fp8_f32(
                SCALE_A * v[0], SCALE_A * v[1], 0, false);
            pk = __builtin_amdgcn_cvt_pk_fp8_f32(
                SCALE_A * v[2], SCALE_A * v[3], pk, true);
            a[rg] = pk;
        }
        ss += __shfl_xor(ss, 32, 64);   // partner lane has other k-half
        if (t == 0) af0 = a; else af1 = a;
        if (wq == 0 && lh == 0) x2s[rt * 64 + t * 32 + ll] = ss;
    }
    if (tid < 128) zl[tid] = 0.0f;

    grid.sync();   // meta visible everywhere

    // ---- S1: meta -> LDS ----
    {
        const unsigned int* mo = (const unsigned int*)out;
        #pragma unroll
        for (int i = 0; i < NCENT / 512; ++i) meta_s[tid + i * 512] = mo[tid + i * 512];
    }

    grid.sync();   // everyone has copied meta; safe to overwrite out

    // ---- S2: fp8 B fragments -> out (byte layout identical to R8) ----
    // center n, feature j=lane: byte -> ((c*4+wq)*64 + (n&31) + (j>>5)*32)*32 + (j&31)
    {
        const unsigned int u8 =
            (unsigned int)__builtin_amdgcn_cvt_pk_fp8_f32(cv, cv, 0, false) & 0xffu;
        const int cc  = n >> 7;
        const int wc  = (n >> 5) & 3;
        const int llc = n & 31;
        ((unsigned char*)out)[(size_t)((cc * 4 + wc) * 64 + llc + (lane >> 5) * 32) * 32
                              + (lane & 31)] = (unsigned char)u8;
    }

    // ---- C-init: p = -log2e*||x_row||^2 in C/D layout ----
    const int rb = 4 * lh;
    float16v p0, p1;
    #pragma unroll
    for (int i = 0; i < 16; ++i) {
        const int ri = rb + (i & 3) + 8 * (i >> 2);
        p0[i] = -QS * x2s[rt * 64 + ri];
        p1[i] = -QS * x2s[rt * 64 + 32 + ri];
    }

    grid.sync();   // cb complete and visible

    // ---- S3: main loop ----
    const int zbase = rt * 64 + rb;
    const int moff  = wq * 32 + ll;
    const char* cbb = (const char*)out + (size_t)(wq * 64 + lane) * 32;

    #define SCREEN(AV, TQ, WV, TOFF) do {                                     \
        float m0_ = fmaxf(fmaxf((AV)[0],  (AV)[1]),  (AV)[2]);                \
        float m1_ = fmaxf(fmaxf((AV)[3],  (AV)[4]),  (AV)[5]);                \
        float m2_ = fmaxf(fmaxf((AV)[6],  (AV)[7]),  (AV)[8]);                \
        float m3_ = fmaxf(fmaxf((AV)[9],  (AV)[10]), (AV)[11]);               \
        float m4_ = fmaxf(fmaxf((AV)[12], (AV)[13]), (AV)[14]);               \
        float mx_ = fmaxf(fmaxf(fmaxf(m0_, m1_), m2_),                        \
                          fmaxf(fmaxf(m3_, m4_), (AV)[15]));                  \
        if (__any(mx_ > (TQ))) {                                              \
            if (mx_ > (TQ)) {                                                 \
                const float q_ = TSKIP - (TQ);                                \
                _Pragma("unroll")                                             \
                for (int i_ = 0; i_ < 16; ++i_)                               \
                    atomicAdd(&zl[zbase + (TOFF) + (i_ & 3) + 8 * (i_ >> 2)], \
                              (WV) * EXP2F((AV)[i_] + q_));                   \
            }                                                                 \
        }                                                                     \
    } while (0)

    // prologue: chunks 0,1 resident; 2-deep prefetch after consumption
    int8v pbE = *(const int8v*)(cbb);           // chunk 0
    int8v pbO = *(const int8v*)(cbb + 8192);    // chunk 1
    unsigned int mu0 = meta_s[moff];
    float tq_p = __uint_as_float(mu0 & 0xffff0000u);
    float w_p  = __uint_as_float(mu0 << 16);
    float16v avA = MFMA(af0, pbE, p0);          // c0.t0
    float16v avB = MFMA(af1, pbE, p1);          // c0.t1
    pbE = *(const int8v*)(cbb + 2 * 8192);      // chunk 2 (even slot)
    SCREEN(avA, tq_p, w_p, 0);                  // c0.t0 (one-time latency hit)

    #define BODY(C, PB, DOLOAD) do {                                          \
        const unsigned int mu_ = meta_s[(C) * 128 + moff];                    \
        const float tq_c = __uint_as_float(mu_ & 0xffff0000u);                \
        const float w_c  = __uint_as_float(mu_ << 16);                        \
        float16v nA = MFMA(af0, PB, p0);                                      \
        SCREEN(avB, tq_p, w_p, 32);            /* (C-1).t1 */                 \
        float16v nB = MFMA(af1, PB, p1);                                      \
        if (DOLOAD) PB = *(const int8v*)(cbb + (size_t)((C) + 2) * 8192);     \
        SCREEN(nA, tq_c, w_c, 0);              /* (C).t0  */                  \
        avB = nB; tq_p = tq_c; w_p = w_c;                                     \
    } while (0)

    for (int c2 = 1; c2 < 31; c2 += 2) {        // chunks 1..30
        BODY(c2,     pbO, (c2 + 2 <= 31));
        BODY(c2 + 1, pbE, (c2 + 3 <= 31));
    }
    {   // peel chunk 31 (odd slot)
        const unsigned int mu_ = meta_s[31 * 128 + moff];
        const float tq_c = __uint_as_float(mu_ & 0xffff0000u);
        const float w_c  = __uint_as_float(mu_ << 16);
        float16v nA = MFMA(af0, pbO, p0);
        SCREEN(avB, tq_p, w_p, 32);             // c30.t1
        float16v nB = MFMA(af1, pbO, p1);
        SCREEN(nA, tq_c, w_c, 0);               // c31.t0
        SCREEN(nB, tq_c, w_c, 32);              // c31.t1
    }
    #undef BODY
    #undef SCREEN

    grid.sync();   // all reads of cb done; safe to write results into out

    // ---- S4: sigmoid + store ----
    if (tid < 128) {
        const float z = zl[tid] + bptr[0];
        out[bid * 128 + tid] = 1.0f / (1.0f + EXP2F(-QS * z));
    }
}

// ====================== fallback (R8, uses workspace) ======================
__global__ __launch_bounds__(256) void rbf_prep(
    const float* __restrict__ xb, const float* __restrict__ w,
    char* __restrict__ cb, float2v* __restrict__ hc2w) {
    const int bid = blockIdx.x;
    const int tid = threadIdx.x;
    if (bid < 128) {
        const int o      = bid * 256 + tid;
        const int col    = o >> 3;
        const int joct   = o & 7;
        const int c      = col >> 7;
        const int w4     = (col >> 5) & 3;
        const int lanelo = col & 31;
        const int l      = lanelo + (joct >> 2) * 32;
        const int j0     = (joct & 3) * 8;
        const float* src = xb + col * MFEAT + joct * 8;
        float4v v0 = *(const float4v*)(src);
        float4v v1 = *(const float4v*)(src + 4);
        int lo = __builtin_amdgcn_cvt_pk_fp8_f32(v0[0], v0[1], 0, false);
        lo     = __builtin_amdgcn_cvt_pk_fp8_f32(v0[2], v0[3], lo, true);
        int hi = __builtin_amdgcn_cvt_pk_fp8_f32(v1[0], v1[1], 0, false);
        hi     = __builtin_amdgcn_cvt_pk_fp8_f32(v1[2], v1[3], hi, true);
        unsigned long long pk = (unsigned long long)(unsigned)lo |
                                ((unsigned long long)(unsigned)hi << 32);
        *(unsigned long long*)(cb + (size_t)((c * 4 + w4) * 64 + l) * 32 + j0) = pk;
    } else {
        const int row  = (bid - 128) * 4 + (tid >> 6);
        const int lane = tid & 63;
        float v = xb[row * MFEAT + lane];
        float s = v * v;
        #pragma unroll
        for (int off = 32; off > 0; off >>= 1) s += __shfl_xor(s, off, 64);
        if (lane == 0) {
            float2v hw = {-QS * s, w[row]};
            hc2w[row] = hw;
        }
    }
}

__global__ __launch_bounds__(256, 4) void rbf_main(
    const float* __restrict__ x, const char* __restrict__ cb,
    const float2v* __restrict__ hc2w, const float* __restrict__ bptr,
    float* __restrict__ out) {
    __shared__ float x2s[64];
    __shared__ float zl[64];

    const int tid  = threadIdx.x;
    const int wave = tid >> 6;
    const int lane = tid & 63;
    const int ll   = lane & 31;
    const int lh   = lane >> 5;
    const int r0   = (int)blockIdx.x * 64;

    if (tid < 64) zl[tid] = 0.0f;

    int8v af[2];
    float ssv[2];
    #pragma unroll
    for (int t = 0; t < 2; ++t) {
        const float* xr = x + (size_t)(r0 + t * 32 + ll) * MFEAT + lh * 32;
        int8v a;
        float ss = 0.0f;
        #pragma unroll
        for (int rg = 0; rg < 8; ++rg) {
            float4v v = *(const float4v*)(xr + rg * 4);
            ss = fmaf(v[0], v[0], ss); ss = fmaf(v[1], v[1], ss);
            ss = fmaf(v[2], v[2], ss); ss = fmaf(v[3], v[3], ss);
            int pk = __builtin_amdgcn_cvt_pk_fp8_f32(
                SCALE_A * v[0], SCALE_A * v[1], 0, false);
            pk = __builtin_amdgcn_cvt_pk_fp8_f32(
                SCALE_A * v[2], SCALE_A * v[3], pk, true);
            a[rg] = pk;
        }
        ss += __shfl_xor(ss, 32, 64);
        af[t]  = a;
        ssv[t] = ss;
    }
    if (wave == 0 && lh == 0) {
        x2s[ll]      = ssv[0];
        x2s[32 + ll] = ssv[1];
    }
    __syncthreads();

    const int rb = 4 * lh;
    float16v p0, p1;
    #pragma unroll
    for (int i = 0; i < 16; ++i) {
        const int ri = rb + (i & 3) + 8 * (i >> 2);
        p0[i] = -QS * x2s[ri];
        p1[i] = -QS * x2s[32 + ri];
    }

    const char* cbb = cb + wave * 2048 + lane * 32;
    const float2v* hwp = hc2w + wave * 32 + ll;

    int8v   pb[2];
    float2v phw[2];

    #define LOADB(c, s) do {                               \
        pb[s] = *(const int8v*)(cbb + (c) * 8192);         \
        float2v hw_ = hwp[(c) * 128];                      \
        hw_.x = TSKIP - hw_.x;                             \
        phw[s] = hw_;                                      \
    } while (0)

    LOADB(0, 0);

    #pragma unroll 2
    for (int c = 0; c < NCHUNK; ++c) {
        const int cur = c & 1, nxt = cur ^ 1;
        if (c + 1 < NCHUNK) LOADB(c + 1, nxt);
        float16v a0 = MFMA(af[0], pb[cur], p0);
        float16v a1 = MFMA(af[1], pb[cur], p1);
        const float tq = phw[cur].x;
        const float wvv = phw[cur].y;
        #pragma unroll
        for (int t = 0; t < 2; ++t) {
            float16v av = t ? a1 : a0;
            float m0 = fmaxf(fmaxf(av[0],  av[1]),  av[2]);
            float m1 = fmaxf(fmaxf(av[3],  av[4]),  av[5]);
            float m2 = fmaxf(fmaxf(av[6],  av[7]),  av[8]);
            float m3 = fmaxf(fmaxf(av[9],  av[10]), av[11]);
            float m4 = fmaxf(fmaxf(av[12], av[13]), av[14]);
            float mx = fmaxf(fmaxf(fmaxf(m0, m1), m2),
                             fmaxf(fmaxf(m3, m4), av[15]));
            if (__any(mx > tq)) {
                if (mx > tq) {
                    const float q = TSKIP - tq;
                    #pragma unroll
                    for (int i = 0; i < 16; ++i)
                        atomicAdd(&zl[t * 32 + rb + (i & 3) + 8 * (i >> 2)],
                                  wvv * EXP2F(av[i] + q));
                }
            }
        }
    }
    #undef LOADB

    __syncthreads();
    if (tid < 64) {
        float z = zl[tid] + bptr[0];
        out[r0 + tid] = 1.0f / (1.0f + EXP2F(-QS * z));
    }
}

// ================================ launcher =================================
extern "C" void kernel_launch(void* const* d_in, const int* in_sizes, int n_in,
                              void* d_out, int out_size, void* d_ws, size_t ws_size,
                              hipStream_t stream) {
    const float* x  = (const float*)d_in[0];   // [K, M]
    const float* xb = (const float*)d_in[1];   // [N, M]
    const float* w  = (const float*)d_in[2];   // [1, N]
    const float* b  = (const float*)d_in[3];   // [1]
    float* out = (float*)d_out;                // [K]

    void* kargs[5] = {(void*)&x, (void*)&xb, (void*)&w, (void*)&b, (void*)&out};
    hipError_t err = hipLaunchCooperativeKernel(
        (const void*)rbf_fused, dim3(512), dim3(512), kargs, 0, stream);
    if (err != hipSuccess) {
        (void)hipGetLastError();   // clear, fall back to ws path
        char*    cb   = (char*)d_ws;                               // 256 KB fp8
        float2v* hc2w = (float2v*)((char*)d_ws + NCENT * MFEAT);   // 32 KB
        rbf_prep<<<128 + NCENT / 4, 256, 0, stream>>>(xb, w, cb, hc2w);
        rbf_main<<<KOBS / 64, 256, 0, stream>>>(x, cb, hc2w, b, out);
    }
}

// Round 4
// 208.070 us; speedup vs baseline: 1.5053x; 1.5053x over previous
//
#include <hip/hip_runtime.h>
#include <hip/hip_cooperative_groups.h>

namespace cg = cooperative_groups;

// LogisticRegressionRBF: out[k] = sigmoid( sum_n w[n]*exp(-||x_k - c_n||^2) + b )
// K=65536, N=4096, M=64. fp32 in/out.
//
// R11 = R10 with the compile fix: __builtin_amdgcn_cvt_pk_f32_fp8's second
// operand must be a LITERAL constant -> selector moved to a template param.
// R10 recap: keep R9's storage plan (cb fp8 staged in the OUTPUT buffer, no
// d_ws -> no 256 MiB poison fill), with R8's PROVEN loop shape (simple
// ping-pong, screen after both MFMAs, 2 live f32x16 accs, VGPR ~64 -- R9's
// staggered screen spilled accumulators: WRITE_SIZE 597 MB, 242 us).
// Meta table eliminated:
//   - w[n] read directly from input w (16 KB, L2-resident), prefetched
//   - tq = TSKIP + log2e*||c_q||^2 computed on the fly from the B-fragment
//     in registers (quantized norm = self-consistent; threshold shift ~6
//     log2 units around -60 -> decisions flip only for mass < 2^-54)
// Fallback: R8 two-kernel ws path if cooperative launch is rejected.

#define KOBS 65536
#define NCENT 4096
#define MFEAT 64
#define NCHUNK 32                    // 4096 / 128 centers per chunk

#define SCALE_A 2.8853900817779268f  // 2*log2(e)
#define QS      1.4426950408889634f  // log2(e)
#define TSKIP   -60.0f

typedef __attribute__((ext_vector_type(4)))  float float4v;
typedef __attribute__((ext_vector_type(2)))  float float2v;
typedef __attribute__((ext_vector_type(16))) float float16v;
typedef __attribute__((ext_vector_type(8)))  int   int8v;

#if __has_builtin(__builtin_amdgcn_exp2f)
#define EXP2F(x) __builtin_amdgcn_exp2f(x)
#else
#define EXP2F(x) exp2f(x)
#endif

// fp8(e4m3) pair -> 2x f32, for ||c_q||^2 on the fly. HI selects word.
#if __has_builtin(__builtin_amdgcn_cvt_pk_f32_fp8)
template <bool HI>
static __device__ inline float2v cvt2_fp8(int v) {
    return __builtin_amdgcn_cvt_pk_f32_fp8(v, HI);   // HI is a literal here
}
#else
static __device__ inline float fp8_dec(unsigned b) {   // e4m3fn, denorm->0
    unsigned e = (b >> 3) & 15u, m = b & 7u, s = b >> 7;
    if (!e) return 0.0f;
    return __uint_as_float((s << 31) | ((e + 120u) << 23) | (m << 20));
}
template <bool HI>
static __device__ inline float2v cvt2_fp8(int v) {
    unsigned u = (unsigned)v >> (HI ? 16 : 0);
    float2v r; r.x = fp8_dec(u & 0xffu); r.y = fp8_dec((u >> 8) & 0xffu);
    return r;
}
#endif

#define MFMA(A, B, C) __builtin_amdgcn_mfma_scale_f32_32x32x64_f8f6f4( \
    (A), (B), (C), 0, 0, 0, 0x7f7f7f7f, 0, 0x7f7f7f7f)

// ============================ fused cooperative kernel =====================
// grid 512 x block 512 (proven launchable in R9). Block: 128 output rows.
// Wave wv: rt = wv>>2 row-tile (64 rows), wq = wv&3 center quarter.
__global__ __launch_bounds__(512, 4) void rbf_fused(
    const float* __restrict__ x, const float* __restrict__ xb,
    const float* __restrict__ w, const float* __restrict__ bptr,
    float* __restrict__ out) {
    __shared__ float x2s[128];
    __shared__ float zl[128];

    const int tid  = threadIdx.x;
    const int wv   = tid >> 6;
    const int lane = tid & 63;
    const int ll   = lane & 31;
    const int lh   = lane >> 5;
    const int rt   = wv >> 2;
    const int wq   = wv & 3;
    const int bid  = (int)blockIdx.x;

    cg::grid_group grid = cg::this_grid();

    if (tid < 128) zl[tid] = 0.0f;

    // ---- P0a: quantize xb -> fp8 B-fragments into out (R8 prep layout).
    // One octet per thread of wave 0: o = bid*64 + tid, 512*64 = 32768 octets.
    if (tid < 64) {
        const int o    = bid * 64 + tid;
        const int col  = o >> 3;              // center index
        const int joct = o & 7;               // k0 = joct*8
        const int cc   = col >> 7;
        const int w4   = (col >> 5) & 3;
        const int llc  = col & 31;
        const int l    = llc + (joct >> 2) * 32;
        const int j0   = (joct & 3) * 8;
        const float* src = xb + col * MFEAT + joct * 8;
        float4v v0 = *(const float4v*)(src);
        float4v v1 = *(const float4v*)(src + 4);
        int lo = __builtin_amdgcn_cvt_pk_fp8_f32(v0[0], v0[1], 0, false);
        lo     = __builtin_amdgcn_cvt_pk_fp8_f32(v0[2], v0[3], lo, true);
        int hi = __builtin_amdgcn_cvt_pk_fp8_f32(v1[0], v1[1], 0, false);
        hi     = __builtin_amdgcn_cvt_pk_fp8_f32(v1[2], v1[3], hi, true);
        unsigned long long pk = (unsigned long long)(unsigned)lo |
                                ((unsigned long long)(unsigned)hi << 32);
        *(unsigned long long*)((char*)out +
            (size_t)((cc * 4 + w4) * 64 + l) * 32 + j0) = pk;
    }

    // ---- P0b: A fragments (fp8, pre-scaled by 2*log2e) + row norms ----
    // A-frag layout 32x32x64: lane l holds row l&31, k = (l>>5)*32 + byte.
    const int r0e = bid * 128 + rt * 64;
    int8v af0, af1;
    #pragma unroll
    for (int t = 0; t < 2; ++t) {
        const float* xr = x + (size_t)(r0e + t * 32 + ll) * MFEAT + lh * 32;
        int8v a;
        float ss = 0.0f;
        #pragma unroll
        for (int rg = 0; rg < 8; ++rg) {
            float4v v = *(const float4v*)(xr + rg * 4);
            ss = fmaf(v[0], v[0], ss); ss = fmaf(v[1], v[1], ss);
            ss = fmaf(v[2], v[2], ss); ss = fmaf(v[3], v[3], ss);
            int pk = __builtin_amdgcn_cvt_pk_fp8_f32(
                SCALE_A * v[0], SCALE_A * v[1], 0, false);
            pk = __builtin_amdgcn_cvt_pk_fp8_f32(
                SCALE_A * v[2], SCALE_A * v[3], pk, true);
            a[rg] = pk;
        }
        ss += __shfl_xor(ss, 32, 64);   // partner lane has other k-half
        if (t == 0) af0 = a; else af1 = a;
        if (wq == 0 && lh == 0) x2s[rt * 64 + t * 32 + ll] = ss;
    }

    grid.sync();   // cb complete + visible; x2s ready

    // ---- C-init: p = -log2e*||x_row||^2 in C/D layout ----
    // row = (reg&3) + 8*(reg>>2) + 4*(lane>>5)  [+ t*32]
    const int rb = 4 * lh;
    float16v p0, p1;
    #pragma unroll
    for (int i = 0; i < 16; ++i) {
        const int ri = rb + (i & 3) + 8 * (i >> 2);
        p0[i] = -QS * x2s[rt * 64 + ri];
        p1[i] = -QS * x2s[rt * 64 + 32 + ri];
    }

    // ---- P1: main loop (R8-proven shape) ----
    const int zbase = rt * 64 + rb;
    const char*  cbb = (const char*)out + (size_t)(wq * 64 + lane) * 32;
    const float* wp  = w + wq * 32 + ll;

    int8v pb[2];
    float tqv[2], wvv[2];

    #define LOADB(c, s) do {                                   \
        pb[s]  = *(const int8v*)(cbb + (size_t)(c) * 8192);    \
        wvv[s] = wp[(c) * 128];                                \
    } while (0)

    // tq from the fragment itself: ||c_q||^2 over this lane's 32 fp8 values,
    // combined with the partner k-half lane. Two partial chains for ILP.
    #define TQC(s) do {                                        \
        float s0_ = 0.0f, s1_ = 0.0f;                          \
        _Pragma("unroll")                                      \
        for (int d_ = 0; d_ < 8; ++d_) {                       \
            float2v f0_ = cvt2_fp8<false>(pb[s][d_]);          \
            float2v f1_ = cvt2_fp8<true>(pb[s][d_]);           \
            s0_ = fmaf(f0_.x, f0_.x, s0_);                     \
            s1_ = fmaf(f0_.y, f0_.y, s1_);                     \
            s0_ = fmaf(f1_.x, f1_.x, s0_);                     \
            s1_ = fmaf(f1_.y, f1_.y, s1_);                     \
        }                                                      \
        float st_ = s0_ + s1_;                                 \
        st_ += __shfl_xor(st_, 32, 64);                        \
        tqv[s] = TSKIP + QS * st_;                             \
    } while (0)

    LOADB(0, 0);
    TQC(0);            // one-time load stall

    #pragma unroll 2
    for (int c = 0; c < NCHUNK; ++c) {
        const int cur = c & 1, nxt = cur ^ 1;
        if (c + 1 < NCHUNK) LOADB(c + 1, nxt);
        float16v a0 = MFMA(af0, pb[cur], p0);
        float16v a1 = MFMA(af1, pb[cur], p1);
        if (c + 1 < NCHUNK) TQC(nxt);      // runs in the MFMA shadow
        const float tq = tqv[cur];
        const float wv_ = wvv[cur];
        #pragma unroll
        for (int t = 0; t < 2; ++t) {
            float16v av = t ? a1 : a0;
            float m0 = fmaxf(fmaxf(av[0],  av[1]),  av[2]);
            float m1 = fmaxf(fmaxf(av[3],  av[4]),  av[5]);
            float m2 = fmaxf(fmaxf(av[6],  av[7]),  av[8]);
            float m3 = fmaxf(fmaxf(av[9],  av[10]), av[11]);
            float m4 = fmaxf(fmaxf(av[12], av[13]), av[14]);
            float mx = fmaxf(fmaxf(fmaxf(m0, m1), m2),
                             fmaxf(fmaxf(m3, m4), av[15]));
            if (__any(mx > tq)) {          // rare: ~1e-4 of tiles
                if (mx > tq) {
                    const float q = TSKIP - tq;
                    #pragma unroll
                    for (int i = 0; i < 16; ++i)
                        atomicAdd(&zl[zbase + t * 32 + (i & 3) + 8 * (i >> 2)],
                                  wv_ * EXP2F(av[i] + q));
                }
            }
        }
    }
    #undef LOADB
    #undef TQC

    grid.sync();   // all cb reads done; safe to overwrite out

    // ---- P2: sigmoid + store ----
    if (tid < 128) {
        const float z = zl[tid] + bptr[0];
        out[bid * 128 + tid] = 1.0f / (1.0f + EXP2F(-QS * z));
    }
}

// ====================== fallback (R8, uses workspace) ======================
__global__ __launch_bounds__(256) void rbf_prep(
    const float* __restrict__ xb, const float* __restrict__ w,
    char* __restrict__ cb, float2v* __restrict__ hc2w) {
    const int bid = blockIdx.x;
    const int tid = threadIdx.x;
    if (bid < 128) {
        const int o      = bid * 256 + tid;
        const int col    = o >> 3;
        const int joct   = o & 7;
        const int c      = col >> 7;
        const int w4     = (col >> 5) & 3;
        const int lanelo = col & 31;
        const int l      = lanelo + (joct >> 2) * 32;
        const int j0     = (joct & 3) * 8;
        const float* src = xb + col * MFEAT + joct * 8;
        float4v v0 = *(const float4v*)(src);
        float4v v1 = *(const float4v*)(src + 4);
        int lo = __builtin_amdgcn_cvt_pk_fp8_f32(v0[0], v0[1], 0, false);
        lo     = __builtin_amdgcn_cvt_pk_fp8_f32(v0[2], v0[3], lo, true);
        int hi = __builtin_amdgcn_cvt_pk_fp8_f32(v1[0], v1[1], 0, false);
        hi     = __builtin_amdgcn_cvt_pk_fp8_f32(v1[2], v1[3], hi, true);
        unsigned long long pk = (unsigned long long)(unsigned)lo |
                                ((unsigned long long)(unsigned)hi << 32);
        *(unsigned long long*)(cb + (size_t)((c * 4 + w4) * 64 + l) * 32 + j0) = pk;
    } else {
        const int row  = (bid - 128) * 4 + (tid >> 6);
        const int lane = tid & 63;
        float v = xb[row * MFEAT + lane];
        float s = v * v;
        #pragma unroll
        for (int off = 32; off > 0; off >>= 1) s += __shfl_xor(s, off, 64);
        if (lane == 0) {
            float2v hw = {-QS * s, w[row]};
            hc2w[row] = hw;
        }
    }
}

__global__ __launch_bounds__(256, 4) void rbf_main(
    const float* __restrict__ x, const char* __restrict__ cb,
    const float2v* __restrict__ hc2w, const float* __restrict__ bptr,
    float* __restrict__ out) {
    __shared__ float x2s[64];
    __shared__ float zl[64];

    const int tid  = threadIdx.x;
    const int wave = tid >> 6;
    const int lane = tid & 63;
    const int ll   = lane & 31;
    const int lh   = lane >> 5;
    const int r0   = (int)blockIdx.x * 64;

    if (tid < 64) zl[tid] = 0.0f;

    int8v af[2];
    float ssv[2];
    #pragma unroll
    for (int t = 0; t < 2; ++t) {
        const float* xr = x + (size_t)(r0 + t * 32 + ll) * MFEAT + lh * 32;
        int8v a;
        float ss = 0.0f;
        #pragma unroll
        for (int rg = 0; rg < 8; ++rg) {
            float4v v = *(const float4v*)(xr + rg * 4);
            ss = fmaf(v[0], v[0], ss); ss = fmaf(v[1], v[1], ss);
            ss = fmaf(v[2], v[2], ss); ss = fmaf(v[3], v[3], ss);
            int pk = __builtin_amdgcn_cvt_pk_fp8_f32(
                SCALE_A * v[0], SCALE_A * v[1], 0, false);
            pk = __builtin_amdgcn_cvt_pk_fp8_f32(
                SCALE_A * v[2], SCALE_A * v[3], pk, true);
            a[rg] = pk;
        }
        ss += __shfl_xor(ss, 32, 64);
        af[t]  = a;
        ssv[t] = ss;
    }
    if (wave == 0 && lh == 0) {
        x2s[ll]      = ssv[0];
        x2s[32 + ll] = ssv[1];
    }
    __syncthreads();

    const int rb = 4 * lh;
    float16v p0, p1;
    #pragma unroll
    for (int i = 0; i < 16; ++i) {
        const int ri = rb + (i & 3) + 8 * (i >> 2);
        p0[i] = -QS * x2s[ri];
        p1[i] = -QS * x2s[32 + ri];
    }

    const char* cbb = cb + wave * 2048 + lane * 32;
    const float2v* hwp = hc2w + wave * 32 + ll;

    int8v   pb[2];
    float2v phw[2];

    #define LOADB(c, s) do {                               \
        pb[s] = *(const int8v*)(cbb + (c) * 8192);         \
        float2v hw_ = hwp[(c) * 128];                      \
        hw_.x = TSKIP - hw_.x;                             \
        phw[s] = hw_;                                      \
    } while (0)

    LOADB(0, 0);

    #pragma unroll 2
    for (int c = 0; c < NCHUNK; ++c) {
        const int cur = c & 1, nxt = cur ^ 1;
        if (c + 1 < NCHUNK) LOADB(c + 1, nxt);
        float16v a0 = MFMA(af[0], pb[cur], p0);
        float16v a1 = MFMA(af[1], pb[cur], p1);
        const float tq = phw[cur].x;
        const float wvv = phw[cur].y;
        #pragma unroll
        for (int t = 0; t < 2; ++t) {
            float16v av = t ? a1 : a0;
            float m0 = fmaxf(fmaxf(av[0],  av[1]),  av[2]);
            float m1 = fmaxf(fmaxf(av[3],  av[4]),  av[5]);
            float m2 = fmaxf(fmaxf(av[6],  av[7]),  av[8]);
            float m3 = fmaxf(fmaxf(av[9],  av[10]), av[11]);
            float m4 = fmaxf(fmaxf(av[12], av[13]), av[14]);
            float mx = fmaxf(fmaxf(fmaxf(m0, m1), m2),
                             fmaxf(fmaxf(m3, m4), av[15]));
            if (__any(mx > tq)) {
                if (mx > tq) {
                    const float q = TSKIP - tq;
                    #pragma unroll
                    for (int i = 0; i < 16; ++i)
                        atomicAdd(&zl[t * 32 + rb + (i & 3) + 8 * (i >> 2)],
                                  wvv * EXP2F(av[i] + q));
                }
            }
        }
    }
    #undef LOADB

    __syncthreads();
    if (tid < 64) {
        float z = zl[tid] + bptr[0];
        out[r0 + tid] = 1.0f / (1.0f + EXP2F(-QS * z));
    }
}

// ================================ launcher =================================
extern "C" void kernel_launch(void* const* d_in, const int* in_sizes, int n_in,
                              void* d_out, int out_size, void* d_ws, size_t ws_size,
                              hipStream_t stream) {
    const float* x  = (const float*)d_in[0];   // [K, M]
    const float* xb = (const float*)d_in[1];   // [N, M]
    const float* w  = (const float*)d_in[2];   // [1, N]
    const float* b  = (const float*)d_in[3];   // [1]
    float* out = (float*)d_out;                // [K]

    void* kargs[5] = {(void*)&x, (void*)&xb, (void*)&w, (void*)&b, (void*)&out};
    hipError_t err = hipLaunchCooperativeKernel(
        (const void*)rbf_fused, dim3(512), dim3(512), kargs, 0, stream);
    if (err != hipSuccess) {
        (void)hipGetLastError();   // clear, fall back to ws path
        char*    cb   = (char*)d_ws;                               // 256 KB fp8
        float2v* hc2w = (float2v*)((char*)d_ws + NCENT * MFEAT);   // 32 KB
        rbf_prep<<<128 + NCENT / 4, 256, 0, stream>>>(xb, w, cb, hc2w);
        rbf_main<<<KOBS / 64, 256, 0, stream>>>(x, cb, hc2w, b, out);
    }
}

// Round 5
// 91.093 us; speedup vs baseline: 3.4384x; 2.2841x over previous
//
#include <hip/hip_runtime.h>

// LogisticRegressionRBF: out[k] = sigmoid( sum_n w[n]*exp(-||x_k - c_n||^2) + b )
// K=65536, N=4096, M=64. fp32 in/out.
//
// R12: abandon cooperative fusion. R9/R11 algebra: grid.sync ~= 55 us EACH
// (R9 = 4 syncs + loop = 242; R11 = 2 syncs + loop = 131 -> loop ~= 21 us,
// sync ~= 55 us; WRITE_SIZE was KB -- 0.6 MB, never any spills). The 256 MiB
// ws poison-fill (~43 us) appears to be charged unconditionally (R4 total
// 208 = kernel 131 + ~77 of fills/overhead despite no ws use), so using d_ws
// costs nothing extra. Structure:
//   kernel 1 (rbf_prep, ~5 us): xb -> fp8 B-fragments (R8-proven layout) in
//     d_ws + meta table {tq = TSKIP + log2e*||c||^2, w} (tq precomputed).
//   kernel 2 (rbf_main, ~20 us): R11's empirically-fast loop geometry
//     (512 thr x 512 blocks, 128 rows/block, waves rt(2) x wq(4), VGPR 60,
//     124/128 unified regs -> no deeper prefetch) with meta from the table
//     (drops TQC's per-iter vmcnt(0) dependency), no grid.syncs.
// Loop: ping-pong B prefetch, 2 independent 32x32x64 MX-fp8 MFMAs/chunk
// (C-init = -log2e*||x||^2), 16-max screen, rare-hit LDS atomic accumulate.

#define KOBS 65536
#define NCENT 4096
#define MFEAT 64
#define NCHUNK 32                    // 4096 / 128 centers per chunk

#define SCALE_A 2.8853900817779268f  // 2*log2(e)
#define QS      1.4426950408889634f  // log2(e)
#define TSKIP   -60.0f

typedef __attribute__((ext_vector_type(4)))  float float4v;
typedef __attribute__((ext_vector_type(2)))  float float2v;
typedef __attribute__((ext_vector_type(16))) float float16v;
typedef __attribute__((ext_vector_type(8)))  int   int8v;

#if __has_builtin(__builtin_amdgcn_exp2f)
#define EXP2F(x) __builtin_amdgcn_exp2f(x)
#else
#define EXP2F(x) exp2f(x)
#endif

#define MFMA(A, B, C) __builtin_amdgcn_mfma_scale_f32_32x32x64_f8f6f4( \
    (A), (B), (C), 0, 0, 0, 0x7f7f7f7f, 0, 0x7f7f7f7f)

// ================================ prep =====================================
// Blocks [0,128): transpose+quantize xb fp32 -> fp8 e4m3 B-fragments.
// Blocks [128,1152): hc2w[n] = { TSKIP + log2e*||c_n||^2, w[n] }.
__global__ __launch_bounds__(256) void rbf_prep(
    const float* __restrict__ xb, const float* __restrict__ w,
    char* __restrict__ cb, float2v* __restrict__ hc2w) {
    const int bid = blockIdx.x;
    const int tid = threadIdx.x;
    if (bid < 128) {
        const int o      = bid * 256 + tid;   // (center, k-octet), [0, 32768)
        const int col    = o >> 3;            // center index
        const int joct   = o & 7;             // k0 = joct*8
        const int c      = col >> 7;          // chunk
        const int w4     = (col >> 5) & 3;    // wave-quarter within chunk
        const int lanelo = col & 31;
        const int l      = lanelo + (joct >> 2) * 32;  // lane (k-half select)
        const int j0     = (joct & 3) * 8;             // byte offset in 32B
        const float* src = xb + col * MFEAT + joct * 8;
        float4v v0 = *(const float4v*)(src);
        float4v v1 = *(const float4v*)(src + 4);
        int lo = __builtin_amdgcn_cvt_pk_fp8_f32(v0[0], v0[1], 0, false);
        lo     = __builtin_amdgcn_cvt_pk_fp8_f32(v0[2], v0[3], lo, true);
        int hi = __builtin_amdgcn_cvt_pk_fp8_f32(v1[0], v1[1], 0, false);
        hi     = __builtin_amdgcn_cvt_pk_fp8_f32(v1[2], v1[3], hi, true);
        unsigned long long pk = (unsigned long long)(unsigned)lo |
                                ((unsigned long long)(unsigned)hi << 32);
        *(unsigned long long*)(cb + (size_t)((c * 4 + w4) * 64 + l) * 32 + j0) = pk;
    } else {
        const int row  = (bid - 128) * 4 + (tid >> 6);
        const int lane = tid & 63;
        float v = xb[row * MFEAT + lane];
        float s = v * v;
        #pragma unroll
        for (int off = 32; off > 0; off >>= 1) s += __shfl_xor(s, off, 64);
        if (lane == 0) {
            float2v hw = {TSKIP + QS * s, w[row]};   // tq precomputed
            hc2w[row] = hw;
        }
    }
}

// ================================ main =====================================
// grid 512 x block 512 (R11-proven loop geometry). Block: 128 output rows.
// Wave wv: rt = wv>>2 row-tile (64 rows), wq = wv&3 center quarter.
__global__ __launch_bounds__(512, 4) void rbf_main(
    const float* __restrict__ x, const char* __restrict__ cb,
    const float2v* __restrict__ hc2w, const float* __restrict__ bptr,
    float* __restrict__ out) {
    __shared__ float x2s[128];
    __shared__ float zl[128];

    const int tid  = threadIdx.x;
    const int wv   = tid >> 6;
    const int lane = tid & 63;
    const int ll   = lane & 31;
    const int lh   = lane >> 5;
    const int rt   = wv >> 2;
    const int wq   = wv & 3;
    const int bid  = (int)blockIdx.x;

    if (tid < 128) zl[tid] = 0.0f;

    // ---- A fragments (fp8, pre-scaled by 2*log2e) + row norms ----
    // A-frag layout 32x32x64: lane l holds row l&31, k = (l>>5)*32 + byte.
    const int r0e = bid * 128 + rt * 64;
    int8v af0, af1;
    #pragma unroll
    for (int t = 0; t < 2; ++t) {
        const float* xr = x + (size_t)(r0e + t * 32 + ll) * MFEAT + lh * 32;
        int8v a;
        float ss = 0.0f;
        #pragma unroll
        for (int rg = 0; rg < 8; ++rg) {
            float4v v = *(const float4v*)(xr + rg * 4);
            ss = fmaf(v[0], v[0], ss); ss = fmaf(v[1], v[1], ss);
            ss = fmaf(v[2], v[2], ss); ss = fmaf(v[3], v[3], ss);
            int pk = __builtin_amdgcn_cvt_pk_fp8_f32(
                SCALE_A * v[0], SCALE_A * v[1], 0, false);
            pk = __builtin_amdgcn_cvt_pk_fp8_f32(
                SCALE_A * v[2], SCALE_A * v[3], pk, true);
            a[rg] = pk;
        }
        ss += __shfl_xor(ss, 32, 64);   // partner lane has other k-half
        if (t == 0) af0 = a; else af1 = a;
        if (wq == 0 && lh == 0) x2s[rt * 64 + t * 32 + ll] = ss;
    }
    __syncthreads();

    // ---- C-init: p = -log2e*||x_row||^2 in C/D layout ----
    // row = (reg&3) + 8*(reg>>2) + 4*(lane>>5)  [+ t*32]
    const int rb = 4 * lh;
    float16v p0, p1;
    #pragma unroll
    for (int i = 0; i < 16; ++i) {
        const int ri = rb + (i & 3) + 8 * (i >> 2);
        p0[i] = -QS * x2s[rt * 64 + ri];
        p1[i] = -QS * x2s[rt * 64 + 32 + ri];
    }

    // ---- main loop ----
    const int zbase = rt * 64 + rb;
    const char*    cbb = cb + (size_t)(wq * 64 + lane) * 32;
    const float2v* hwp = hc2w + wq * 32 + ll;

    int8v   pb[2];
    float2v phw[2];   // {tq, w}

    #define LOADB(c, s) do {                                   \
        pb[s]  = *(const int8v*)(cbb + (size_t)(c) * 8192);    \
        phw[s] = hwp[(c) * 128];                               \
    } while (0)

    LOADB(0, 0);

    #pragma unroll 2
    for (int c = 0; c < NCHUNK; ++c) {
        const int cur = c & 1, nxt = cur ^ 1;
        if (c + 1 < NCHUNK) LOADB(c + 1, nxt);
        float16v a0 = MFMA(af0, pb[cur], p0);
        float16v a1 = MFMA(af1, pb[cur], p1);
        const float tq  = phw[cur].x;
        const float wv_ = phw[cur].y;
        #pragma unroll
        for (int t = 0; t < 2; ++t) {
            float16v av = t ? a1 : a0;
            float m0 = fmaxf(fmaxf(av[0],  av[1]),  av[2]);
            float m1 = fmaxf(fmaxf(av[3],  av[4]),  av[5]);
            float m2 = fmaxf(fmaxf(av[6],  av[7]),  av[8]);
            float m3 = fmaxf(fmaxf(av[9],  av[10]), av[11]);
            float m4 = fmaxf(fmaxf(av[12], av[13]), av[14]);
            float mx = fmaxf(fmaxf(fmaxf(m0, m1), m2),
                             fmaxf(fmaxf(m3, m4), av[15]));
            if (__any(mx > tq)) {          // rare: ~1e-4 of tiles
                if (mx > tq) {
                    const float q = TSKIP - tq;   // = -log2e*||c||^2
                    #pragma unroll
                    for (int i = 0; i < 16; ++i)
                        atomicAdd(&zl[zbase + t * 32 + (i & 3) + 8 * (i >> 2)],
                                  wv_ * EXP2F(av[i] + q));
                }
            }
        }
    }
    #undef LOADB

    // ---- combine, sigmoid, store ----
    __syncthreads();
    if (tid < 128) {
        const float z = zl[tid] + bptr[0];
        out[bid * 128 + tid] = 1.0f / (1.0f + EXP2F(-QS * z));
    }
}

// ================================ launcher =================================
extern "C" void kernel_launch(void* const* d_in, const int* in_sizes, int n_in,
                              void* d_out, int out_size, void* d_ws, size_t ws_size,
                              hipStream_t stream) {
    const float* x  = (const float*)d_in[0];   // [K, M]
    const float* xb = (const float*)d_in[1];   // [N, M]
    const float* w  = (const float*)d_in[2];   // [1, N]
    const float* b  = (const float*)d_in[3];   // [1]
    float* out = (float*)d_out;                // [K]

    char*    cb   = (char*)d_ws;                               // 256 KB fp8
    float2v* hc2w = (float2v*)((char*)d_ws + NCENT * MFEAT);   // 32 KB

    rbf_prep<<<128 + NCENT / 4, 256, 0, stream>>>(xb, w, cb, hc2w);
    rbf_main<<<KOBS / 128, 512, 0, stream>>>(x, cb, hc2w, b, out);
}

// Round 6
// 88.234 us; speedup vs baseline: 3.5498x; 1.0324x over previous
//
#include <hip/hip_runtime.h>

// LogisticRegressionRBF: out[k] = sigmoid( sum_n w[n]*exp(-||x_k - c_n||^2) + b )
// K=65536, N=4096, M=64. fp32 in/out.
//
// R13: attack the main loop's two structural stalls diagnosed from R11's
// loop-phase counters (VALUBusy ~44%, MfmaUtil ~18%, ~145 VALU instr/chunk):
//   1. depth-1 ping-pong -> ring-3 register prefetch (load chunk c+2 at iter
//      c: ~2 iterations (~300 cyc) latency budget >= L2 ~250 cyc, vs ~130
//      before -> removes the per-iteration vmcnt stall). Hand-unrolled with
//      LITERAL slot indices (runtime-indexed ext_vector arrays go to scratch).
//   2. per-chunk VALU diet: meta packed to 1 reg {bf16 tq | bf16 w} (bf16
//      threshold shift <=0.5 log2, buried in the -60 margin), 32-bit
//      saddr-form addressing (uniform SGPR base + unsigned voffset, no 64-bit
//      per-lane adds), ONE ballot per chunk (combined 2-tile max) instead of
//      two, max3-shaped 7-op trees.
// Reg ledger: VGPR ~63 + AGPR 64 (p0/p1 + 2 live acc) ~= 127 <= 128 cap from
// __launch_bounds__(512,4) -> 16 waves/CU retained. WRITE_SIZE is the spill
// tripwire (should stay ~0.5 MB).
// ws poison-fill (43 us) is unconditional -> two-kernel ws path is free.

#define KOBS 65536
#define NCENT 4096
#define MFEAT 64
#define NCHUNK 32                    // 4096 / 128 centers per chunk

#define SCALE_A 2.8853900817779268f  // 2*log2(e)
#define QS      1.4426950408889634f  // log2(e)
#define TSKIP   -60.0f

typedef __attribute__((ext_vector_type(4)))  float float4v;
typedef __attribute__((ext_vector_type(16))) float float16v;
typedef __attribute__((ext_vector_type(8)))  int   int8v;

#if __has_builtin(__builtin_amdgcn_exp2f)
#define EXP2F(x) __builtin_amdgcn_exp2f(x)
#else
#define EXP2F(x) exp2f(x)
#endif

static __device__ inline unsigned f2bfu(float f) {
    unsigned u = __float_as_uint(f);
    return (u + 0x7fffu + ((u >> 16) & 1u)) >> 16;
}

#define MFMA(A, B, C) __builtin_amdgcn_mfma_scale_f32_32x32x64_f8f6f4( \
    (A), (B), (C), 0, 0, 0, 0x7f7f7f7f, 0, 0x7f7f7f7f)

// ================================ prep =====================================
// Blocks [0,128): transpose+quantize xb fp32 -> fp8 e4m3 B-fragments.
// Blocks [128,1152): hcw[n] = { bf16(TSKIP + log2e*||c_n||^2) | bf16(w[n]) }.
__global__ __launch_bounds__(256) void rbf_prep(
    const float* __restrict__ xb, const float* __restrict__ w,
    char* __restrict__ cb, unsigned* __restrict__ hcw) {
    const int bid = blockIdx.x;
    const int tid = threadIdx.x;
    if (bid < 128) {
        const int o      = bid * 256 + tid;   // (center, k-octet), [0, 32768)
        const int col    = o >> 3;            // center index
        const int joct   = o & 7;             // k0 = joct*8
        const int c      = col >> 7;          // chunk
        const int w4     = (col >> 5) & 3;    // wave-quarter within chunk
        const int lanelo = col & 31;
        const int l      = lanelo + (joct >> 2) * 32;  // lane (k-half select)
        const int j0     = (joct & 3) * 8;             // byte offset in 32B
        const float* src = xb + col * MFEAT + joct * 8;
        float4v v0 = *(const float4v*)(src);
        float4v v1 = *(const float4v*)(src + 4);
        int lo = __builtin_amdgcn_cvt_pk_fp8_f32(v0[0], v0[1], 0, false);
        lo     = __builtin_amdgcn_cvt_pk_fp8_f32(v0[2], v0[3], lo, true);
        int hi = __builtin_amdgcn_cvt_pk_fp8_f32(v1[0], v1[1], 0, false);
        hi     = __builtin_amdgcn_cvt_pk_fp8_f32(v1[2], v1[3], hi, true);
        unsigned long long pk = (unsigned long long)(unsigned)lo |
                                ((unsigned long long)(unsigned)hi << 32);
        *(unsigned long long*)(cb + (size_t)((c * 4 + w4) * 64 + l) * 32 + j0) = pk;
    } else {
        const int row  = (bid - 128) * 4 + (tid >> 6);
        const int lane = tid & 63;
        float v = xb[row * MFEAT + lane];
        float s = v * v;
        #pragma unroll
        for (int off = 32; off > 0; off >>= 1) s += __shfl_xor(s, off, 64);
        if (lane == 0)
            hcw[row] = (f2bfu(TSKIP + QS * s) << 16) | f2bfu(w[row]);
    }
}

// ================================ main =====================================
// grid 512 x block 512. Block: 128 output rows.
// Wave wv: rt = wv>>2 row-tile (64 rows), wq = wv&3 center quarter.
__global__ __launch_bounds__(512, 4) void rbf_main(
    const float* __restrict__ x, const char* __restrict__ cb,
    const unsigned* __restrict__ hcw, const float* __restrict__ bptr,
    float* __restrict__ out) {
    __shared__ float x2s[128];
    __shared__ float zl[128];

    const int tid  = threadIdx.x;
    const int wv   = tid >> 6;
    const int lane = tid & 63;
    const int ll   = lane & 31;
    const int lh   = lane >> 5;
    const int rt   = wv >> 2;
    const int wq   = wv & 3;
    const int bid  = (int)blockIdx.x;

    if (tid < 128) zl[tid] = 0.0f;

    // ---- A fragments (fp8, pre-scaled by 2*log2e) + row norms ----
    // A-frag layout 32x32x64: lane l holds row l&31, k = (l>>5)*32 + byte.
    const int r0e = bid * 128 + rt * 64;
    int8v af0, af1;
    #pragma unroll
    for (int t = 0; t < 2; ++t) {
        const float* xr = x + (size_t)(r0e + t * 32 + ll) * MFEAT + lh * 32;
        int8v a;
        float ss = 0.0f;
        #pragma unroll
        for (int rg = 0; rg < 8; ++rg) {
            float4v v = *(const float4v*)(xr + rg * 4);
            ss = fmaf(v[0], v[0], ss); ss = fmaf(v[1], v[1], ss);
            ss = fmaf(v[2], v[2], ss); ss = fmaf(v[3], v[3], ss);
            int pk = __builtin_amdgcn_cvt_pk_fp8_f32(
                SCALE_A * v[0], SCALE_A * v[1], 0, false);
            pk = __builtin_amdgcn_cvt_pk_fp8_f32(
                SCALE_A * v[2], SCALE_A * v[3], pk, true);
            a[rg] = pk;
        }
        ss += __shfl_xor(ss, 32, 64);   // partner lane has other k-half
        if (t == 0) af0 = a; else af1 = a;
        if (wq == 0 && lh == 0) x2s[rt * 64 + t * 32 + ll] = ss;
    }
    __syncthreads();

    // ---- C-init: p = -log2e*||x_row||^2 in C/D layout ----
    // row = (reg&3) + 8*(reg>>2) + 4*(lane>>5)  [+ t*32]
    const int rb = 4 * lh;
    float16v p0, p1;
    #pragma unroll
    for (int i = 0; i < 16; ++i) {
        const int ri = rb + (i & 3) + 8 * (i >> 2);
        p0[i] = -QS * x2s[rt * 64 + ri];
        p1[i] = -QS * x2s[rt * 64 + 32 + ri];
    }

    // ---- main loop: ring-3 register prefetch, literal slot indices ----
    const int zbase = rt * 64 + rb;
    const unsigned cboff = (unsigned)(wq * 64 + lane) * 32u;  // voffset, saddr form
    const unsigned moff  = (unsigned)(wq * 32 + ll);

    int8v    pb[3];
    unsigned mw[3];

    #define LOADB(C, S) do {                                               \
        pb[S] = *(const int8v*)(cb + cboff + (unsigned)(C) * 8192u);       \
        mw[S] = hcw[moff + (unsigned)(C) * 128u];                          \
    } while (0)

    #define STEP(C, SCUR, SPRE, DOLOAD) do {                               \
        if (DOLOAD) LOADB((C) + 2, SPRE);                                  \
        float16v a0 = MFMA(af0, pb[SCUR], p0);                             \
        float16v a1 = MFMA(af1, pb[SCUR], p1);                             \
        const unsigned mu = mw[SCUR];                                      \
        const float tq  = __uint_as_float(mu & 0xffff0000u);               \
        const float wv_ = __uint_as_float(mu << 16);                       \
        float uA0 = fmaxf(fmaxf(a0[0],  a0[1]),  a0[2]);                   \
        float uA1 = fmaxf(fmaxf(a0[3],  a0[4]),  a0[5]);                   \
        float uA2 = fmaxf(fmaxf(a0[6],  a0[7]),  a0[8]);                   \
        float uA3 = fmaxf(fmaxf(a0[9],  a0[10]), a0[11]);                  \
        float uA4 = fmaxf(fmaxf(a0[12], a0[13]), a0[14]);                  \
        float mA  = fmaxf(fmaxf(fmaxf(uA0, uA1), uA2),                     \
                          fmaxf(fmaxf(uA3, uA4), a0[15]));                 \
        float uB0 = fmaxf(fmaxf(a1[0],  a1[1]),  a1[2]);                   \
        float uB1 = fmaxf(fmaxf(a1[3],  a1[4]),  a1[5]);                   \
        float uB2 = fmaxf(fmaxf(a1[6],  a1[7]),  a1[8]);                   \
        float uB3 = fmaxf(fmaxf(a1[9],  a1[10]), a1[11]);                  \
        float uB4 = fmaxf(fmaxf(a1[12], a1[13]), a1[14]);                  \
        float mB  = fmaxf(fmaxf(fmaxf(uB0, uB1), uB2),                     \
                          fmaxf(fmaxf(uB3, uB4), a1[15]));                 \
        if (__any(fmaxf(mA, mB) > tq)) {       /* one ballot per chunk */  \
            const float q = TSKIP - tq;        /* = -log2e*||c||^2 */      \
            if (mA > tq) {                                                 \
                _Pragma("unroll")                                          \
                for (int i_ = 0; i_ < 16; ++i_)                            \
                    atomicAdd(&zl[zbase + (i_ & 3) + 8 * (i_ >> 2)],       \
                              wv_ * EXP2F(a0[i_] + q));                    \
            }                                                              \
            if (mB > tq) {                                                 \
                _Pragma("unroll")                                          \
                for (int i_ = 0; i_ < 16; ++i_)                            \
                    atomicAdd(&zl[zbase + 32 + (i_ & 3) + 8 * (i_ >> 2)],  \
                              wv_ * EXP2F(a1[i_] + q));                    \
            }                                                              \
        }                                                                  \
    } while (0)

    LOADB(0, 0);
    LOADB(1, 1);

    #pragma unroll 1
    for (int c = 0; c < 30; c += 3) {    // chunks 0..29; slot = chunk % 3
        STEP(c,     0, 2, 1);
        STEP(c + 1, 1, 0, 1);
        STEP(c + 2, 2, 1, 1);
    }
    STEP(30, 0, 2, 0);                   // peeled, no prefetch
    STEP(31, 1, 0, 0);

    #undef STEP
    #undef LOADB

    // ---- combine, sigmoid, store ----
    __syncthreads();
    if (tid < 128) {
        const float z = zl[tid] + bptr[0];
        out[bid * 128 + tid] = 1.0f / (1.0f + EXP2F(-QS * z));
    }
}

// ================================ launcher =================================
extern "C" void kernel_launch(void* const* d_in, const int* in_sizes, int n_in,
                              void* d_out, int out_size, void* d_ws, size_t ws_size,
                              hipStream_t stream) {
    const float* x  = (const float*)d_in[0];   // [K, M]
    const float* xb = (const float*)d_in[1];   // [N, M]
    const float* w  = (const float*)d_in[2];   // [1, N]
    const float* b  = (const float*)d_in[3];   // [1]
    float* out = (float*)d_out;                // [K]

    char*     cb  = (char*)d_ws;                               // 256 KB fp8
    unsigned* hcw = (unsigned*)((char*)d_ws + NCENT * MFEAT);  // 16 KB packed meta

    rbf_prep<<<128 + NCENT / 4, 256, 0, stream>>>(xb, w, cb, hcw);
    rbf_main<<<KOBS / 128, 512, 0, stream>>>(x, cb, hcw, b, out);
}